// Round 8
// baseline (987.235 us; speedup 1.0000x reference)
//
#include <hip/hip_runtime.h>
#include <cfloat>

typedef unsigned short u16;
typedef unsigned int   u32;

#define NB   2
#define N1   4096
#define N2   32768
#define C1   128
#define C2   64
#define CIN  192      // C1 + C2
#define F1   128
#define F2   128
#define ROW0 131      // 3 + C1 (fp32)
#define ROW1 67       // 3 + C2 (fp32)
#define NQ   (NB * N2)   // 65536 total query points
#define EPSF 1e-07f

// stable top-3 insert (strict <): earlier index wins ties, matching lax.top_k.
__device__ __forceinline__ void ins3(float d, int gi,
    float& d0, float& d1, float& d2, int& i0, int& i1, int& i2) {
  if (d < d2) {
    if (d < d1) {
      d2 = d1; i2 = i1;
      if (d < d0) { d1 = d0; i1 = i0; d0 = d; i0 = gi; }
      else        { d1 = d;  i1 = gi; }
    } else { d2 = d; i2 = gi; }
  }
}

struct KW { int i0, i1, i2; float w0, w1, w2; };   // 24 B per query

// ---- K1: brute-force kNN, 1 thread per query, coords staged in LDS -------------
__global__ __launch_bounds__(256) void knn_kernel(const float* __restrict__ in0,
                                                  const float* __restrict__ in1,
                                                  KW* __restrict__ kw) {
  __shared__ float lx[N1], ly[N1], lz[N1];   // 49,152 B
  int t = threadIdx.x;
  int q = blockIdx.x * 256 + t;
  int b = q >> 15;                            // uniform per block
  for (int j = t; j < N1; j += 256) {
    const float* r = in0 + (size_t)(b * N1 + j) * ROW0;
    lx[j] = r[0]; ly[j] = r[1]; lz[j] = r[2];
  }
  __syncthreads();
  int n = q & (N2 - 1);
  const float* qr = in1 + (size_t)(b * N2 + n) * ROW1;
  float qx = qr[0], qy = qr[1], qz = qr[2];
  float d0 = FLT_MAX, d1 = FLT_MAX, d2 = FLT_MAX;
  int   i0 = 0, i1 = 0, i2 = 0;
#pragma unroll 4
  for (int j = 0; j < N1; j++) {
    float dx = qx - lx[j], dy = qy - ly[j], dz = qz - lz[j];
    // exact numpy order, no FMA contraction: (dx^2 + dy^2) + dz^2
    float d = __fadd_rn(__fadd_rn(__fmul_rn(dx, dx), __fmul_rn(dy, dy)),
                        __fmul_rn(dz, dz));
    ins3(d, j, d0, d1, d2, i0, i1, i2);
  }
  float a0 = fmaxf(d0, EPSF), a1 = fmaxf(d1, EPSF), a2 = fmaxf(d2, EPSF);
  float w0 = 1.f / a0, w1 = 1.f / a1, w2 = 1.f / a2;
  float s = __fadd_rn(__fadd_rn(w0, w1), w2);
  KW o; o.i0 = i0; o.i1 = i1; o.i2 = i2;
  o.w0 = w0 / s; o.w1 = w1 / s; o.w2 = w2 / s;
  kw[q] = o;
}

// ---- K2: interp + concat + MLP1 + MLP2, pure fp32 VALU, fp32 output ------------
// block = 256 threads, 32 queries; x and h tiles in LDS (40,960 B).
__global__ __launch_bounds__(256) void interp_mlp(
    const float* __restrict__ in0, const float* __restrict__ in1,
    const KW* __restrict__ kw,
    const float* __restrict__ W1, const float* __restrict__ b1,
    const float* __restrict__ W2, const float* __restrict__ b2,
    float* __restrict__ out) {
  __shared__ float xls[32][CIN];   // 24,576 B
  __shared__ float hls[32][F1];    // 16,384 B
  int t = threadIdx.x;
  int qb = blockIdx.x * 32;
  int b = qb >> 15;                // uniform per block (32768 % 32 == 0)

  // interp + concat (numpy op order, fp32 throughout)
  for (int e = t; e < 32 * CIN; e += 256) {
    int ql = e / CIN, c = e % CIN;
    int q = qb + ql, n = q & (N2 - 1);
    float v;
    if (c < C1) {
      KW k = kw[q];
      const float* base = in0 + (size_t)b * N1 * ROW0 + 3 + c;
      float g0 = base[(size_t)k.i0 * ROW0];
      float g1 = base[(size_t)k.i1 * ROW0];
      float g2 = base[(size_t)k.i2 * ROW0];
      v = __fadd_rn(__fadd_rn(__fmul_rn(k.w0, g0), __fmul_rn(k.w1, g1)),
                    __fmul_rn(k.w2, g2));
    } else {
      v = in1[(size_t)(b * N2 + n) * ROW1 + 3 + (c - C1)];
    }
    xls[ql][c] = v;
  }
  __syncthreads();

  // MLP1: h = relu(x @ W1 + b1), fp32 FMA
  for (int e = t; e < 32 * F1; e += 256) {
    int ql = e / F1, j = e % F1;
    float s = b1[j];
    for (int c = 0; c < CIN; c++) s = fmaf(xls[ql][c], W1[c * F1 + j], s);
    hls[ql][j] = fmaxf(s, 0.f);
  }
  __syncthreads();

  // MLP2: out = relu(h @ W2 + b2), fp32 FMA, fp32 store
  for (int e = t; e < 32 * F2; e += 256) {
    int ql = e / F2, j = e % F2;
    float s = b2[j];
    for (int c = 0; c < F1; c++) s = fmaf(hls[ql][c], W2[c * F2 + j], s);
    out[(size_t)(qb + ql) * F2 + j] = fmaxf(s, 0.f);
  }
}

// ---- K3: xyz2 passthrough fp32 -> fp32 ----------------------------------------
__global__ void xyz_copy(const float* __restrict__ in1, float* __restrict__ out) {
  int q = blockIdx.x * blockDim.x + threadIdx.x;
  if (q < NQ) {
    const float* r = in1 + (size_t)q * ROW1;
    float* o = out + (size_t)NQ * F2 + (size_t)q * 3;
    o[0] = r[0]; o[1] = r[1]; o[2] = r[2];
  }
}

extern "C" void kernel_launch(void* const* d_in, const int* in_sizes, int n_in,
                              void* d_out, int out_size, void* d_ws, size_t ws_size,
                              hipStream_t stream) {
  // input assignment by element count (invariant to ordering); fallback positional
  const float *in0 = nullptr, *in1 = nullptr, *W1 = nullptr, *W2 = nullptr;
  const float *b1 = nullptr, *b2 = nullptr;
  for (int i = 0; i < n_in; i++) {
    const float* p = (const float*)d_in[i];
    switch (in_sizes[i]) {
      case 2 * N1 * ROW0: in0 = p; break;          // 1,073,152
      case 2 * N2 * ROW1: in1 = p; break;          // 4,390,912
      case CIN * F1:      W1  = p; break;          // 24,576
      case F1 * F2:       W2  = p; break;          // 16,384
      case F1:            (b1 ? b2 : b1) = p; break;  // 128 (b1 first)
      default: break;
    }
  }
  if (!in0) in0 = (const float*)d_in[0];
  if (!in1) in1 = (const float*)d_in[1];
  if (!W1)  W1  = (const float*)d_in[2];
  if (!b1)  b1  = (const float*)d_in[3];
  if (!W2)  W2  = (const float*)d_in[4];
  if (!b2)  b2  = (const float*)d_in[5];

  float* out = (float*)d_out;   // fp32: x (65536*128) ++ xyz2 (65536*3)
  KW* kw = (KW*)d_ws;           // 1,572,864 B

  knn_kernel<<<dim3(NQ / 256), dim3(256), 0, stream>>>(in0, in1, kw);
  interp_mlp<<<dim3(NQ / 32), dim3(256), 0, stream>>>(in0, in1, kw, W1, b1, W2, b2, out);
  xyz_copy<<<dim3((NQ + 255) / 256), dim3(256), 0, stream>>>(in1, out);
}

// Round 9
// 440.277 us; speedup vs baseline: 2.2423x; 2.2423x over previous
//
#include <hip/hip_runtime.h>
#include <cfloat>

typedef unsigned short u16;
typedef unsigned int   u32;
typedef __attribute__((ext_vector_type(8))) short short8;
typedef __attribute__((ext_vector_type(4))) float float4_;

#define NB   2
#define N1   4096
#define N2   32768
#define C1   128
#define C2   64
#define CIN  192      // C1 + C2
#define F1   128
#define F2   128
#define ROW0 131      // 3 + C1 (fp32)
#define ROW1 67       // 3 + C2 (fp32)
#define NQ   (NB * N2)   // 65536 total query points
#define EPSF 1e-07f
#define KSPLIT 4
#define KCH  (N1 / KSPLIT)   // 1024 candidates per tile
#define PADX 200      // LDS x-tile pitch (u16): 400 B = 25*16, 16B-aligned rows
#define PADH 136      // LDS h-tile pitch (u16): 272 B = 17*16

// round-to-nearest-even fp32 -> bf16 (finite data only)
__device__ __forceinline__ u16 f2bf(float f) {
  u32 x = __float_as_uint(f);
  return (u16)((x + 0x7fffu + ((x >> 16) & 1u)) >> 16);
}

// stable top-3 insert (strict <): earlier index wins ties, matching lax.top_k.
__device__ __forceinline__ void ins3(float d, int gi,
    float& d0, float& d1, float& d2, int& i0, int& i1, int& i2) {
  if (d < d2) {
    if (d < d1) {
      d2 = d1; i2 = i1;
      if (d < d0) { d1 = d0; i1 = i0; d0 = d; i0 = gi; }
      else        { d1 = d;  i1 = gi; }
    } else { d2 = d; i2 = gi; }
  }
}

struct Part { float d0, d1, d2; int i0, i1, i2; };   // 24 B
struct KW   { int i0, i1, i2; float w0, w1, w2; };   // 24 B

// ---- repack: fp32 weights -> transposed bf16 (80 KB of ws) ---------------------
__global__ void repack_w(const float* __restrict__ W1, const float* __restrict__ W2,
                         u16* __restrict__ W1t, u16* __restrict__ W2t) {
  int i = blockIdx.x * 256 + threadIdx.x;
  if (i < F1 * CIN) { int n = i / CIN, k = i % CIN; W1t[i] = f2bf(W1[k * F1 + n]); }
  if (i < F2 * F1)  { int n = i / F1,  k = i % F1;  W2t[i] = f2bf(W2[k * F2 + n]); }
}

// ---- K1: kNN partial top-3 over one 1024-candidate tile ------------------------
// grid (NQ/256, KSPLIT): 1024 blocks -> 4 blocks/CU, 16 waves/CU.
__global__ __launch_bounds__(256) void knn_part(const float* __restrict__ in0,
                                                const float* __restrict__ in1,
                                                Part* __restrict__ part) {
  __shared__ __align__(16) float4 cs[KCH];   // 16 KB
  int t = threadIdx.x;
  int q = blockIdx.x * 256 + t;
  int ct = blockIdx.y;
  int b = q >> 15;                            // uniform per block
  int c0 = ct * KCH;
  for (int j = t; j < KCH; j += 256) {
    const float* r = in0 + (size_t)(b * N1 + c0 + j) * ROW0;
    cs[j] = make_float4(r[0], r[1], r[2], 0.f);
  }
  __syncthreads();
  int n = q & (N2 - 1);
  const float* qr = in1 + (size_t)(b * N2 + n) * ROW1;
  float qx = qr[0], qy = qr[1], qz = qr[2];
  float d0 = FLT_MAX, d1 = FLT_MAX, d2 = FLT_MAX;
  int   i0 = 0, i1 = 0, i2 = 0;
#pragma unroll 4
  for (int j = 0; j < KCH; j++) {
    float4 cc = cs[j];                        // wave-uniform: LDS broadcast
    float dx = qx - cc.x, dy = qy - cc.y, dz = qz - cc.z;
    // exact numpy order, no FMA contraction: (dx^2 + dy^2) + dz^2
    float d = __fadd_rn(__fadd_rn(__fmul_rn(dx, dx), __fmul_rn(dy, dy)),
                        __fmul_rn(dz, dz));
    ins3(d, c0 + j, d0, d1, d2, i0, i1, i2);
  }
  Part p; p.d0 = d0; p.d1 = d1; p.d2 = d2; p.i0 = i0; p.i1 = i1; p.i2 = i2;
  part[((size_t)q << 2) + ct] = p;
}

// ---- K2: merge partials (ascending tile order preserves tie stability) ---------
__global__ __launch_bounds__(256) void knn_merge(const Part* __restrict__ part,
                                                 KW* __restrict__ kw) {
  int q = blockIdx.x * 256 + threadIdx.x;
  float d0 = FLT_MAX, d1 = FLT_MAX, d2 = FLT_MAX;
  int   i0 = 0, i1 = 0, i2 = 0;
#pragma unroll
  for (int ct = 0; ct < KSPLIT; ct++) {
    Part p = part[((size_t)q << 2) + ct];
    ins3(p.d0, p.i0, d0, d1, d2, i0, i1, i2);
    ins3(p.d1, p.i1, d0, d1, d2, i0, i1, i2);
    ins3(p.d2, p.i2, d0, d1, d2, i0, i1, i2);
  }
  float a0 = fmaxf(d0, EPSF), a1 = fmaxf(d1, EPSF), a2 = fmaxf(d2, EPSF);
  float w0 = 1.f / a0, w1 = 1.f / a1, w2 = 1.f / a2;
  float s = __fadd_rn(__fadd_rn(w0, w1), w2);
  KW o; o.i0 = i0; o.i1 = i1; o.i2 = i2;
  o.w0 = w0 / s; o.w1 = w1 / s; o.w2 = w2 / s;
  kw[q] = o;
}

// ---- K3: interp + concat -> bf16 LDS -> MFMA MLP1 -> MFMA MLP2 -> fp32 out -----
// block = 256 = 4 waves; each wave owns 16 query rows. 1024 blocks.
__global__ __launch_bounds__(256) void interp_mlp(
    const float* __restrict__ in0, const float* __restrict__ in1,
    const KW* __restrict__ kw,
    const u16* __restrict__ W1t, const float* __restrict__ b1,
    const u16* __restrict__ W2t, const float* __restrict__ b2,
    float* __restrict__ out) {
  __shared__ __align__(16) u16 xs[4][16][PADX];   // 25,600 B
  __shared__ __align__(16) u16 hs[4][16][PADH];   // 17,408 B
  int t = threadIdx.x;
  int wave = t >> 6, lane = t & 63;
  int l16 = lane & 15, quad = lane >> 4;
  int qbase = blockIdx.x * 64 + wave * 16;
  int b = qbase >> 15;                  // uniform per block

  // interp + concat into xs[wave] (16 x 192), fp32 gather, bf16 pack
  for (int qi = 0; qi < 16; qi++) {
    int q = qbase + qi;
    KW k = kw[q];                       // wave-uniform load
    const float* base = in0 + (size_t)b * N1 * ROW0 + 3;
    const float* r0 = base + (size_t)k.i0 * ROW0;
    const float* r1 = base + (size_t)k.i1 * ROW0;
    const float* r2 = base + (size_t)k.i2 * ROW0;
    // channels lane and lane+64
    float lo = __fadd_rn(__fadd_rn(__fmul_rn(k.w0, r0[lane]),
                                   __fmul_rn(k.w1, r1[lane])),
                         __fmul_rn(k.w2, r2[lane]));
    float hi = __fadd_rn(__fadd_rn(__fmul_rn(k.w0, r0[64 + lane]),
                                   __fmul_rn(k.w1, r1[64 + lane])),
                         __fmul_rn(k.w2, r2[64 + lane]));
    xs[wave][qi][lane]      = f2bf(lo);
    xs[wave][qi][64 + lane] = f2bf(hi);
    int n2 = q & (N2 - 1);              // channels 128..191 = points2
    xs[wave][qi][C1 + lane] = f2bf(in1[(size_t)(b * N2 + n2) * ROW1 + 3 + lane]);
  }
  __syncthreads();

  // GEMM1: h = relu(x @ W1 + b1); A from LDS, B from global (L1/L2-resident)
  float4_ acc[8];
#pragma unroll
  for (int nt = 0; nt < 8; nt++) acc[nt] = (float4_)0.f;
#pragma unroll
  for (int k0 = 0; k0 < CIN; k0 += 32) {
    short8 af = *(const short8*)&xs[wave][l16][k0 + quad * 8];
#pragma unroll
    for (int nt = 0; nt < 8; nt++) {
      short8 bf = *(const short8*)(W1t + (size_t)(nt * 16 + l16) * CIN + k0 + quad * 8);
      acc[nt] = __builtin_amdgcn_mfma_f32_16x16x32_bf16(af, bf, acc[nt], 0, 0, 0);
    }
  }
#pragma unroll
  for (int nt = 0; nt < 8; nt++) {
    float bv = b1[nt * 16 + l16];
#pragma unroll
    for (int r = 0; r < 4; r++) {   // C/D: row=quad*4+r, col=nt*16+l16
      hs[wave][quad * 4 + r][nt * 16 + l16] = f2bf(fmaxf(acc[nt][r] + bv, 0.f));
    }
  }
  __syncthreads();

  // GEMM2: y = relu(h @ W2 + b2) -> fp32 global store
  float4_ a2[8];
#pragma unroll
  for (int nt = 0; nt < 8; nt++) a2[nt] = (float4_)0.f;
#pragma unroll
  for (int k0 = 0; k0 < F1; k0 += 32) {
    short8 af = *(const short8*)&hs[wave][l16][k0 + quad * 8];
#pragma unroll
    for (int nt = 0; nt < 8; nt++) {
      short8 bf = *(const short8*)(W2t + (size_t)(nt * 16 + l16) * F1 + k0 + quad * 8);
      a2[nt] = __builtin_amdgcn_mfma_f32_16x16x32_bf16(af, bf, a2[nt], 0, 0, 0);
    }
  }
#pragma unroll
  for (int nt = 0; nt < 8; nt++) {
    float bv = b2[nt * 16 + l16];
#pragma unroll
    for (int r = 0; r < 4; r++) {
      int row = qbase + quad * 4 + r;
      out[(size_t)row * F2 + nt * 16 + l16] = fmaxf(a2[nt][r] + bv, 0.f);
    }
  }
}

// ---- K4: xyz2 passthrough fp32 -> fp32 -----------------------------------------
__global__ void xyz_copy(const float* __restrict__ in1, float* __restrict__ out) {
  int q = blockIdx.x * blockDim.x + threadIdx.x;
  if (q < NQ) {
    const float* r = in1 + (size_t)q * ROW1;
    float* o = out + (size_t)NQ * F2 + (size_t)q * 3;
    o[0] = r[0]; o[1] = r[1]; o[2] = r[2];
  }
}

extern "C" void kernel_launch(void* const* d_in, const int* in_sizes, int n_in,
                              void* d_out, int out_size, void* d_ws, size_t ws_size,
                              hipStream_t stream) {
  // input assignment by element count (ordering-invariant); positional fallback
  const float *in0 = nullptr, *in1 = nullptr, *W1 = nullptr, *W2 = nullptr;
  const float *b1 = nullptr, *b2 = nullptr;
  for (int i = 0; i < n_in; i++) {
    const float* p = (const float*)d_in[i];
    switch (in_sizes[i]) {
      case 2 * N1 * ROW0: in0 = p; break;
      case 2 * N2 * ROW1: in1 = p; break;
      case CIN * F1:      W1  = p; break;
      case F1 * F2:       W2  = p; break;
      case F1:            (b1 ? b2 : b1) = p; break;
      default: break;
    }
  }
  if (!in0) in0 = (const float*)d_in[0];
  if (!in1) in1 = (const float*)d_in[1];
  if (!W1)  W1  = (const float*)d_in[2];
  if (!b1)  b1  = (const float*)d_in[3];
  if (!W2)  W2  = (const float*)d_in[4];
  if (!b2)  b2  = (const float*)d_in[5];

  float* out = (float*)d_out;   // fp32: x (65536*128) ++ xyz2 (65536*3)

  // workspace: W1t 49,152 | W2t 32,768 | kw 1,572,864 | part 6,291,456 = 7.95 MB
  char* ws = (char*)d_ws;
  u16*  W1t  = (u16*)(ws + 0);
  u16*  W2t  = (u16*)(ws + 49152);
  KW*   kw   = (KW*)(ws + 81920);
  Part* part = (Part*)(ws + 1654784);

  repack_w<<<dim3(96), dim3(256), 0, stream>>>(W1, W2, W1t, W2t);
  knn_part<<<dim3(NQ / 256, KSPLIT), dim3(256), 0, stream>>>(in0, in1, part);
  knn_merge<<<dim3(NQ / 256), dim3(256), 0, stream>>>(part, kw);
  interp_mlp<<<dim3(NQ / 64), dim3(256), 0, stream>>>(in0, in1, kw, W1t, b1, W2t, b2, out);
  xyz_copy<<<dim3((NQ + 255) / 256), dim3(256), 0, stream>>>(in1, out);
}

// Round 10
// 273.390 us; speedup vs baseline: 3.6111x; 1.6104x over previous
//
#include <hip/hip_runtime.h>
#include <cfloat>

typedef unsigned short u16;
typedef unsigned int   u32;
typedef __attribute__((ext_vector_type(8))) short short8;
typedef __attribute__((ext_vector_type(4))) float float4_;

#define NB   2
#define N1   4096
#define N2   32768
#define C1   128
#define C2   64
#define CIN  192      // C1 + C2
#define F1   128
#define F2   128
#define ROW0 131      // 3 + C1 (fp32)
#define ROW1 67       // 3 + C2 (fp32)
#define NQ   (NB * N2)   // 65536 total query points
#define EPSF 1e-07f
#define KSPLIT 8
#define KCH  (N1 / KSPLIT)   // 512 candidates per tile
#define PADX 200      // LDS x-tile pitch (u16)
#define PADH 136      // LDS h-tile pitch (u16)

// round-to-nearest-even fp32 -> bf16 (finite data only)
__device__ __forceinline__ u16 f2bf(float f) {
  u32 x = __float_as_uint(f);
  return (u16)((x + 0x7fffu + ((x >> 16) & 1u)) >> 16);
}

// BRANCHLESS stable top-3 insert. Strict <: earlier index wins ties (lax.top_k).
// Case check: d<d0: (d0,d1)->(d1,d2), d->d0 ; d0<=d<d1: d1->d2, d->d1 ;
// d1<=d<d2: d->d2 ; d>=d2: no-op. All via cndmask, no control flow.
__device__ __forceinline__ void ins3b(float d, int gi,
    float& d0, float& d1, float& d2, int& i0, int& i1, int& i2) {
  bool lt0 = d < d0, lt1 = d < d1, lt2 = d < d2;
  d2 = lt1 ? d1 : (lt2 ? d : d2);
  i2 = lt1 ? i1 : (lt2 ? gi : i2);
  d1 = lt0 ? d0 : (lt1 ? d : d1);
  i1 = lt0 ? i0 : (lt1 ? gi : i1);
  d0 = lt0 ? d : d0;
  i0 = lt0 ? gi : i0;
}

struct Part { float d0, d1, d2; int i0, i1, i2; };   // 24 B
struct KW   { int i0, i1, i2; float w0, w1, w2; };   // 24 B

// ---- repack: fp32 weights -> transposed bf16 (80 KB of ws) ---------------------
__global__ void repack_w(const float* __restrict__ W1, const float* __restrict__ W2,
                         u16* __restrict__ W1t, u16* __restrict__ W2t) {
  int i = blockIdx.x * 256 + threadIdx.x;
  if (i < F1 * CIN) { int n = i / CIN, k = i % CIN; W1t[i] = f2bf(W1[k * F1 + n]); }
  if (i < F2 * F1)  { int n = i / F1,  k = i % F1;  W2t[i] = f2bf(W2[k * F2 + n]); }
}

// ---- K1: kNN partial top-3 over one 512-candidate tile -------------------------
// grid (NQ/256, KSPLIT) = 2048 blocks -> 8 blocks/CU, 32 waves/CU (max).
__global__ __launch_bounds__(256) void knn_part(const float* __restrict__ in0,
                                                const float* __restrict__ in1,
                                                Part* __restrict__ part) {
  __shared__ __align__(16) float4 cs[KCH];   // 8 KB
  int t = threadIdx.x;
  int q = blockIdx.x * 256 + t;
  int ct = blockIdx.y;
  int b = q >> 15;                            // uniform per block
  int c0 = ct * KCH;
  for (int j = t; j < KCH; j += 256) {
    const float* r = in0 + (size_t)(b * N1 + c0 + j) * ROW0;
    cs[j] = make_float4(r[0], r[1], r[2], 0.f);
  }
  __syncthreads();
  int n = q & (N2 - 1);
  const float* qr = in1 + (size_t)(b * N2 + n) * ROW1;
  float qx = qr[0], qy = qr[1], qz = qr[2];
  float d0 = FLT_MAX, d1 = FLT_MAX, d2 = FLT_MAX;
  int   i0 = 0, i1 = 0, i2 = 0;
#pragma unroll 4
  for (int j = 0; j < KCH; j++) {
    float4 cc = cs[j];                        // wave-uniform: LDS broadcast
    float dx = qx - cc.x, dy = qy - cc.y, dz = qz - cc.z;
    // exact numpy order, no FMA contraction: (dx^2 + dy^2) + dz^2
    float d = __fadd_rn(__fadd_rn(__fmul_rn(dx, dx), __fmul_rn(dy, dy)),
                        __fmul_rn(dz, dz));
    ins3b(d, c0 + j, d0, d1, d2, i0, i1, i2);
  }
  Part p; p.d0 = d0; p.d1 = d1; p.d2 = d2; p.i0 = i0; p.i1 = i1; p.i2 = i2;
  part[((size_t)q << 3) + ct] = p;
}

// ---- K2: merge partials (ascending tile order preserves tie stability) ---------
__global__ __launch_bounds__(256) void knn_merge(const Part* __restrict__ part,
                                                 KW* __restrict__ kw) {
  int q = blockIdx.x * 256 + threadIdx.x;
  float d0 = FLT_MAX, d1 = FLT_MAX, d2 = FLT_MAX;
  int   i0 = 0, i1 = 0, i2 = 0;
#pragma unroll
  for (int ct = 0; ct < KSPLIT; ct++) {
    Part p = part[((size_t)q << 3) + ct];
    ins3b(p.d0, p.i0, d0, d1, d2, i0, i1, i2);
    ins3b(p.d1, p.i1, d0, d1, d2, i0, i1, i2);
    ins3b(p.d2, p.i2, d0, d1, d2, i0, i1, i2);
  }
  float a0 = fmaxf(d0, EPSF), a1 = fmaxf(d1, EPSF), a2 = fmaxf(d2, EPSF);
  float w0 = 1.f / a0, w1 = 1.f / a1, w2 = 1.f / a2;
  float s = __fadd_rn(__fadd_rn(w0, w1), w2);
  KW o; o.i0 = i0; o.i1 = i1; o.i2 = i2;
  o.w0 = w0 / s; o.w1 = w1 / s; o.w2 = w2 / s;
  kw[q] = o;
}

// ---- K3: interp + concat -> bf16 LDS -> MFMA MLP1 -> MFMA MLP2 -> fp32 out -----
// block = 256 = 4 waves; each wave owns 16 query rows. 1024 blocks.
__global__ __launch_bounds__(256) void interp_mlp(
    const float* __restrict__ in0, const float* __restrict__ in1,
    const KW* __restrict__ kw,
    const u16* __restrict__ W1t, const float* __restrict__ b1,
    const u16* __restrict__ W2t, const float* __restrict__ b2,
    float* __restrict__ out) {
  __shared__ __align__(16) u16 xs[4][16][PADX];   // 25,600 B
  __shared__ __align__(16) u16 hs[4][16][PADH];   // 17,408 B
  int t = threadIdx.x;
  int wave = t >> 6, lane = t & 63;
  int l16 = lane & 15, quad = lane >> 4;
  int qbase = blockIdx.x * 64 + wave * 16;
  int b = qbase >> 15;                  // uniform per block

  // interp + concat into xs[wave] (16 x 192), fp32 gather, bf16 pack
  for (int qi = 0; qi < 16; qi++) {
    int q = qbase + qi;
    KW k = kw[q];                       // wave-uniform load
    const float* base = in0 + (size_t)b * N1 * ROW0 + 3;
    const float* r0 = base + (size_t)k.i0 * ROW0;
    const float* r1 = base + (size_t)k.i1 * ROW0;
    const float* r2 = base + (size_t)k.i2 * ROW0;
    float lo = __fadd_rn(__fadd_rn(__fmul_rn(k.w0, r0[lane]),
                                   __fmul_rn(k.w1, r1[lane])),
                         __fmul_rn(k.w2, r2[lane]));
    float hi = __fadd_rn(__fadd_rn(__fmul_rn(k.w0, r0[64 + lane]),
                                   __fmul_rn(k.w1, r1[64 + lane])),
                         __fmul_rn(k.w2, r2[64 + lane]));
    xs[wave][qi][lane]      = f2bf(lo);
    xs[wave][qi][64 + lane] = f2bf(hi);
    int n2 = q & (N2 - 1);              // channels 128..191 = points2
    xs[wave][qi][C1 + lane] = f2bf(in1[(size_t)(b * N2 + n2) * ROW1 + 3 + lane]);
  }
  __syncthreads();

  // GEMM1: h = relu(x @ W1 + b1); A from LDS, B from global (L1/L2-resident)
  float4_ acc[8];
#pragma unroll
  for (int nt = 0; nt < 8; nt++) acc[nt] = (float4_)0.f;
#pragma unroll
  for (int k0 = 0; k0 < CIN; k0 += 32) {
    short8 af = *(const short8*)&xs[wave][l16][k0 + quad * 8];
#pragma unroll
    for (int nt = 0; nt < 8; nt++) {
      short8 bf = *(const short8*)(W1t + (size_t)(nt * 16 + l16) * CIN + k0 + quad * 8);
      acc[nt] = __builtin_amdgcn_mfma_f32_16x16x32_bf16(af, bf, acc[nt], 0, 0, 0);
    }
  }
#pragma unroll
  for (int nt = 0; nt < 8; nt++) {
    float bv = b1[nt * 16 + l16];
#pragma unroll
    for (int r = 0; r < 4; r++) {   // C/D: row=quad*4+r, col=nt*16+l16
      hs[wave][quad * 4 + r][nt * 16 + l16] = f2bf(fmaxf(acc[nt][r] + bv, 0.f));
    }
  }
  __syncthreads();

  // GEMM2: y = relu(h @ W2 + b2) -> fp32 global store
  float4_ a2[8];
#pragma unroll
  for (int nt = 0; nt < 8; nt++) a2[nt] = (float4_)0.f;
#pragma unroll
  for (int k0 = 0; k0 < F1; k0 += 32) {
    short8 af = *(const short8*)&hs[wave][l16][k0 + quad * 8];
#pragma unroll
    for (int nt = 0; nt < 8; nt++) {
      short8 bf = *(const short8*)(W2t + (size_t)(nt * 16 + l16) * F1 + k0 + quad * 8);
      a2[nt] = __builtin_amdgcn_mfma_f32_16x16x32_bf16(af, bf, a2[nt], 0, 0, 0);
    }
  }
#pragma unroll
  for (int nt = 0; nt < 8; nt++) {
    float bv = b2[nt * 16 + l16];
#pragma unroll
    for (int r = 0; r < 4; r++) {
      int row = qbase + quad * 4 + r;
      out[(size_t)row * F2 + nt * 16 + l16] = fmaxf(a2[nt][r] + bv, 0.f);
    }
  }
}

// ---- K4: xyz2 passthrough fp32 -> fp32 -----------------------------------------
__global__ void xyz_copy(const float* __restrict__ in1, float* __restrict__ out) {
  int q = blockIdx.x * blockDim.x + threadIdx.x;
  if (q < NQ) {
    const float* r = in1 + (size_t)q * ROW1;
    float* o = out + (size_t)NQ * F2 + (size_t)q * 3;
    o[0] = r[0]; o[1] = r[1]; o[2] = r[2];
  }
}

extern "C" void kernel_launch(void* const* d_in, const int* in_sizes, int n_in,
                              void* d_out, int out_size, void* d_ws, size_t ws_size,
                              hipStream_t stream) {
  // input assignment by element count (ordering-invariant); positional fallback
  const float *in0 = nullptr, *in1 = nullptr, *W1 = nullptr, *W2 = nullptr;
  const float *b1 = nullptr, *b2 = nullptr;
  for (int i = 0; i < n_in; i++) {
    const float* p = (const float*)d_in[i];
    switch (in_sizes[i]) {
      case 2 * N1 * ROW0: in0 = p; break;
      case 2 * N2 * ROW1: in1 = p; break;
      case CIN * F1:      W1  = p; break;
      case F1 * F2:       W2  = p; break;
      case F1:            (b1 ? b2 : b1) = p; break;
      default: break;
    }
  }
  if (!in0) in0 = (const float*)d_in[0];
  if (!in1) in1 = (const float*)d_in[1];
  if (!W1)  W1  = (const float*)d_in[2];
  if (!b1)  b1  = (const float*)d_in[3];
  if (!W2)  W2  = (const float*)d_in[4];
  if (!b2)  b2  = (const float*)d_in[5];

  float* out = (float*)d_out;   // fp32: x (65536*128) ++ xyz2 (65536*3)

  // ws: W1t 49,152 | W2t 32,768 | kw 1,572,864 | part 12,582,912  = 13.6 MB
  char* ws = (char*)d_ws;
  u16*  W1t  = (u16*)(ws + 0);
  u16*  W2t  = (u16*)(ws + 49152);
  KW*   kw   = (KW*)(ws + 81920);
  Part* part = (Part*)(ws + 1654784);

  repack_w<<<dim3(96), dim3(256), 0, stream>>>(W1, W2, W1t, W2t);
  knn_part<<<dim3(NQ / 256, KSPLIT), dim3(256), 0, stream>>>(in0, in1, part);
  knn_merge<<<dim3(NQ / 256), dim3(256), 0, stream>>>(part, kw);
  interp_mlp<<<dim3(NQ / 64), dim3(256), 0, stream>>>(in0, in1, kw, W1t, b1, W2t, b2, out);
  xyz_copy<<<dim3((NQ + 255) / 256), dim3(256), 0, stream>>>(in1, out);
}